// Round 9
// baseline (1284.595 us; speedup 1.0000x reference)
//
#include <hip/hip_runtime.h>

#define NN 20000
#define NE 640000

typedef __attribute__((ext_vector_type(4))) float f4;
typedef __attribute__((ext_vector_type(8))) unsigned short us8;
typedef __attribute__((ext_vector_type(8))) __bf16 bf8;
typedef __attribute__((ext_vector_type(4))) int i4;

__device__ __forceinline__ unsigned short f2bf(float f) {
    union { float f; unsigned int u; } v; v.f = f;
    unsigned int u = v.u;
    return (unsigned short)((u + 0x7FFFu + ((u >> 16) & 1u)) >> 16);
}
__device__ __forceinline__ float bf2f(unsigned short b) {
    union { unsigned int u; float f; } v; v.u = ((unsigned int)b) << 16; return v.f;
}
__device__ __forceinline__ f4 mfma16(us8 a, us8 b, f4 c) {
    return __builtin_amdgcn_mfma_f32_16x16x32_bf16(
        __builtin_bit_cast(bf8, a), __builtin_bit_cast(bf8, b), c, 0, 0, 0);
}
__device__ __forceinline__ void split8(f4 a0, f4 a1, us8& h, us8& l) {
#pragma unroll
    for (int j = 0; j < 4; j++) {
        unsigned short hb = f2bf(a0[j]); h[j] = hb; l[j] = f2bf(a0[j] - bf2f(hb));
        unsigned short hb2 = f2bf(a1[j]); h[4 + j] = hb2; l[4 + j] = f2bf(a1[j] - bf2f(hb2));
    }
}

// ---------------- weight prep ----------------
// pqW[f][k] (256x128): f<128 -> eW1[k][f] (P weights); f>=128 -> eW1[128+k][f-128] (Q)
__global__ void __launch_bounds__(256) prep_weights(
    const float* __restrict__ eW1, const float* __restrict__ eW2,
    const float* __restrict__ nW1, const float* __restrict__ nW2,
    const float* __restrict__ cW1,
    unsigned short* __restrict__ pqW, unsigned short* __restrict__ eW2T,
    unsigned short* __restrict__ nW1T, unsigned short* __restrict__ nW2T,
    unsigned short* __restrict__ cW1T, float* __restrict__ ew1last)
{
    int i = blockIdx.x * 256 + threadIdx.x;
    if (i < 32768) {
        int f = i >> 7, k = i & 127;
        float v = (f < 128) ? eW1[k * 128 + f] : eW1[(128 + k) * 128 + (f - 128)];
        pqW[i] = f2bf(v); return;
    }
    i -= 32768;
    if (i < 16384) { int f = i >> 7, k = i & 127; eW2T[i] = f2bf(eW2[k * 128 + f]); return; }
    i -= 16384;
    if (i < 32768) { int f = i >> 8, k = i & 255; nW1T[i] = f2bf(nW1[k * 128 + f]); return; }
    i -= 32768;
    if (i < 16384) { int f = i >> 7, k = i & 127; nW2T[i] = f2bf(nW2[k * 128 + f]); return; }
    i -= 16384;
    if (i < 16384) { int f = i >> 7, k = i & 127; cW1T[i] = f2bf(cW1[k * 128 + f]); return; }
    i -= 16384;
    if (i < 128) { ew1last[i] = eW1[256 * 128 + i]; }
}

// ---------------- embedding + state init ----------------
__global__ void __launch_bounds__(128) embed_init(
    const float* __restrict__ h_in, const float* __restrict__ x_in,
    const float* __restrict__ embW, const float* __restrict__ embB,
    float* __restrict__ h_cur, float* __restrict__ x_cur,
    float* __restrict__ m, float* __restrict__ xu)
{
    int n = blockIdx.x, f = threadIdx.x;
    float acc = embB[f];
#pragma unroll
    for (int p = 0; p < 16; p++) acc += h_in[n * 16 + p] * embW[p * 128 + f];
    h_cur[n * 128 + f] = acc;
    m[n * 128 + f] = 0.f;
    if (f < 3) { x_cur[n * 3 + f] = x_in[n * 3 + f]; xu[n * 3 + f] = 0.f; }
}

// ---------------- CSR sort ----------------
__global__ void __launch_bounds__(256) zero_kernel(int* __restrict__ p, int n) {
    int i = blockIdx.x * 256 + threadIdx.x;
    if (i < n) p[i] = 0;
}

__global__ void __launch_bounds__(256) hist_kernel(const int* __restrict__ eidx,
                                                   int* __restrict__ deg) {
    int e = blockIdx.x * 256 + threadIdx.x;
    if (e < NE) atomicAdd(&deg[eidx[e]], 1);
}

__global__ void __launch_bounds__(1024) scan_kernel(const int* __restrict__ deg,
                                                    int* __restrict__ offs) {
    __shared__ int ssum[1024];
    const int t = threadIdx.x;
    const int base = t * 20;
    int loc[20];
    int s = 0;
#pragma unroll
    for (int i = 0; i < 20; i++) {
        int v = (base + i < NN) ? deg[base + i] : 0;
        loc[i] = s; s += v;
    }
    ssum[t] = s;
    __syncthreads();
    for (int d = 1; d < 1024; d <<= 1) {
        int v = (t >= d) ? ssum[t - d] : 0;
        __syncthreads();
        ssum[t] += v;
        __syncthreads();
    }
    int excl = (t == 0) ? 0 : ssum[t - 1];
#pragma unroll
    for (int i = 0; i < 20; i++)
        if (base + i < NN) offs[base + i] = excl + loc[i];
    if (t == 1023) offs[NN] = ssum[1023];
}

__global__ void __launch_bounds__(256) scatter_kernel(
    const int* __restrict__ eidx, const int* __restrict__ offs,
    int* __restrict__ cursor, int* __restrict__ srow, int* __restrict__ scol)
{
    int e = blockIdx.x * 256 + threadIdx.x;
    if (e >= NE) return;
    int r = eidx[e];
    int pos = offs[r] + atomicAdd(&cursor[r], 1);
    srow[pos] = r;
    scol[pos] = eidx[NE + e];
}

// ---------------- pq_kernel: P(+eb1) fp32 | Q bf16 = h @ pqW^T --------------
__global__ void __launch_bounds__(256, 2) pq_kernel(
    const float* __restrict__ h_cur, const unsigned short* __restrict__ pqW,
    const float* __restrict__ eb1,
    float* __restrict__ Pb, unsigned short* __restrict__ Qb)
{
    __shared__ __align__(16) char smA[32 * 128 * 4];  // 16KB fp32 h tile
    const int t = threadIdx.x;
    const int n0 = blockIdx.x * 32;

#pragma unroll
    for (int i = 0; i < 4; i++) {
        int c = i * 256 + t;              // 0..1023 f4-chunks
        int nd = c >> 5, q = c & 31;
        f4 v = *reinterpret_cast<const f4*>(h_cur + (size_t)(n0 + nd) * 128 + q * 4);
        int dst = (nd * 512 + q * 16) ^ ((nd & 7) << 5);
        *reinterpret_cast<f4*>(smA + dst) = v;
    }
    __syncthreads();

    const int lane = t & 63, w = t >> 6;
    const int lr = lane & 15, lg = lane >> 4;

    us8 ah[2][4], al[2][4];
#pragma unroll
    for (int rb = 0; rb < 2; rb++) {
        int row = rb * 16 + lr;
#pragma unroll
        for (int ks = 0; ks < 4; ks++) {
            int base = (row * 512 + ks * 128 + lg * 32) ^ ((row & 7) << 5);
            f4 a0 = *reinterpret_cast<const f4*>(smA + base);
            f4 a1 = *reinterpret_cast<const f4*>(smA + base + 16);
            split8(a0, a1, ah[rb][ks], al[rb][ks]);
        }
    }
#pragma unroll
    for (int rb = 0; rb < 2; rb++) {
#pragma unroll
        for (int nt = 0; nt < 4; nt++) {
            int feat = w * 64 + nt * 16 + lr;
            const unsigned short* bp = pqW + feat * 128 + lg * 8;
            f4 a = {0.f, 0.f, 0.f, 0.f};
#pragma unroll
            for (int ks = 0; ks < 4; ks++) {
                us8 b = *reinterpret_cast<const us8*>(bp + ks * 32);
                a = mfma16(ah[rb][ks], b, a);
                a = mfma16(al[rb][ks], b, a);
            }
#pragma unroll
            for (int r = 0; r < 4; r++) {
                int n = n0 + rb * 16 + lg * 4 + r;
                if (feat < 128) Pb[(size_t)n * 128 + feat] = a[r] + eb1[feat];
                else            Qb[(size_t)n * 128 + feat - 128] = f2bf(a[r]);
            }
        }
    }
}

// ---------------- edge kernel: 64 edges/block, 4 INDEPENDENT waves ----------
// Each wave: 16 edges, all 128 feats, private 8KB LDS slice, NO barriers.
// Slice layout: z1 bf16 [0,4K) -> overwritten by e_ij fp32 [0,8K) -> z3 bf16 [0,4K).
__global__ void __launch_bounds__(256, 4) edge_kernel(
    const int* __restrict__ srow, const int* __restrict__ scol,
    const float* __restrict__ Pb, const unsigned short* __restrict__ Qb,
    const float* __restrict__ x_cur,
    const unsigned short* __restrict__ eW2T, const unsigned short* __restrict__ cW1T,
    const float* __restrict__ ew1last,
    const float* __restrict__ eb2, const float* __restrict__ cb1,
    const float* __restrict__ cb2, const float* __restrict__ cW2,
    float* __restrict__ m, float* __restrict__ xu)
{
    __shared__ __align__(16) char sm[4 * 8192];
    __shared__ int rowS[4][16];
    __shared__ int colS[4][16];
    __shared__ float rpS[4][16][3];
    __shared__ float rdS[4][16];

    const int t = threadIdx.x;
    const int w = t >> 6, lane = t & 63;
    char* wsm = sm + w * 8192;
    const int e0 = blockIdx.x * 64 + w * 16;

    // ---- meta: lanes 0-15 of each wave (within-wave LDS ordering suffices) ----
    if (lane < 16) {
        int r = srow[e0 + lane], c = scol[e0 + lane];
        rowS[w][lane] = r; colS[w][lane] = c;
        float dx = x_cur[r * 3 + 0] - x_cur[c * 3 + 0];
        float dy = x_cur[r * 3 + 1] - x_cur[c * 3 + 1];
        float dz = x_cur[r * 3 + 2] - x_cur[c * 3 + 2];
        rpS[w][lane][0] = dx; rpS[w][lane][1] = dy; rpS[w][lane][2] = dz;
        rdS[w][lane] = dx * dx + dy * dy + dz * dz;
    }

    // ---- phase A: z1 = relu(P'[row] + Q[col] + rd*wl) -> bf16 LDS [0,4K) ----
    {
        const int e = lane >> 2, s = lane & 3;
        const int r = rowS[w][e], c = colS[w][e];
        const float rd = rdS[w][e];
        const float* pp = Pb + (size_t)r * 128 + s * 32;
        const unsigned short* qp = Qb + (size_t)c * 128 + s * 32;
        const float* wl = ew1last + s * 32;
#pragma unroll
        for (int j = 0; j < 4; j++) {
            f4 p0 = *reinterpret_cast<const f4*>(pp + j * 8);
            f4 p1 = *reinterpret_cast<const f4*>(pp + j * 8 + 4);
            us8 q  = *reinterpret_cast<const us8*>(qp + j * 8);
            f4 w0 = *reinterpret_cast<const f4*>(wl + j * 8);
            f4 w1 = *reinterpret_cast<const f4*>(wl + j * 8 + 4);
            us8 z;
#pragma unroll
            for (int k = 0; k < 4; k++) {
                float a = p0[k] + bf2f((unsigned short)q[k])     + rd * w0[k];
                float b = p1[k] + bf2f((unsigned short)q[4 + k]) + rd * w1[k];
                a = a > 0.f ? a : 0.f;
                b = b > 0.f ? b : 0.f;
                z[k] = f2bf(a); z[4 + k] = f2bf(b);
            }
            int ad = (e * 256 + s * 64 + j * 16) ^ ((e & 7) << 4);
            *reinterpret_cast<us8*>(wsm + ad) = z;
        }
    }

    const int lr = lane & 15, lg = lane >> 4;

    // ---- phase B: GEMM2  e_ij = z1 @ eW2 + eb2 -> fp32 LDS [0,8K) ----
    {
        us8 a2[4];
#pragma unroll
        for (int ks = 0; ks < 4; ks++) {
            int ad = (lr * 256 + ks * 64 + lg * 16) ^ ((lr & 7) << 4);
            a2[ks] = *reinterpret_cast<const us8*>(wsm + ad);
        }
        f4 acc[8];
#pragma unroll
        for (int nt = 0; nt < 8; nt++) {
            int feat = nt * 16 + lr;
            const unsigned short* bp = eW2T + feat * 128 + lg * 8;
            f4 a = {0.f, 0.f, 0.f, 0.f};
#pragma unroll
            for (int ks = 0; ks < 4; ks++)
                a = mfma16(a2[ks], *reinterpret_cast<const us8*>(bp + ks * 32), a);
            acc[nt] = a;
        }
#pragma unroll
        for (int nt = 0; nt < 8; nt++) {
            int feat = nt * 16 + lr;
            float bias = eb2[feat];
#pragma unroll
            for (int r = 0; r < 4; r++) {
                int e = lg * 4 + r;
                int ad = (e * 512 + feat * 4) ^ ((e & 7) << 5);
                *reinterpret_cast<float*>(wsm + ad) = acc[nt][r] + bias;
            }
        }
    }

    // ---- phase C: per-wave m-accum (2 feats/lane, run-aggregated atomics) ----
    {
        const int f0 = lane;
        float acc0 = 0.f, acc1 = 0.f;
        int prow = rowS[w][0];
#pragma unroll
        for (int e = 0; e < 16; e++) {
            int r = rowS[w][e];
            if (r != prow) {
                atomicAdd(&m[(size_t)prow * 128 + f0], acc0);
                atomicAdd(&m[(size_t)prow * 128 + f0 + 64], acc1);
                acc0 = acc1 = 0.f; prow = r;
            }
            acc0 += *reinterpret_cast<const float*>(wsm + ((e * 512 + f0 * 4) ^ ((e & 7) << 5)));
            acc1 += *reinterpret_cast<const float*>(wsm + ((e * 512 + (f0 + 64) * 4) ^ ((e & 7) << 5)));
        }
        atomicAdd(&m[(size_t)prow * 128 + f0], acc0);
        atomicAdd(&m[(size_t)prow * 128 + f0 + 64], acc1);
    }

    // ---- phase D: GEMM3  z3 = relu(e_ij @ cW1 + cb1) -> bf16 LDS [0,4K) ----
    {
        us8 a3[4];
#pragma unroll
        for (int ks = 0; ks < 4; ks++) {
            int base = (lr * 512 + ks * 128 + lg * 32) ^ ((lr & 7) << 5);
            f4 a0 = *reinterpret_cast<const f4*>(wsm + base);
            f4 a1 = *reinterpret_cast<const f4*>(wsm + base + 16);
            us8 h;
#pragma unroll
            for (int j = 0; j < 4; j++) { h[j] = f2bf(a0[j]); h[4 + j] = f2bf(a1[j]); }
            a3[ks] = h;
        }
#pragma unroll
        for (int nt = 0; nt < 8; nt++) {
            int feat = nt * 16 + lr;
            const unsigned short* bp = cW1T + feat * 128 + lg * 8;
            f4 a = {0.f, 0.f, 0.f, 0.f};
#pragma unroll
            for (int ks = 0; ks < 4; ks++)
                a = mfma16(a3[ks], *reinterpret_cast<const us8*>(bp + ks * 32), a);
            float bias = cb1[feat];
#pragma unroll
            for (int r = 0; r < 4; r++) {
                float z = a[r] + bias;
                z = z > 0.f ? z : 0.f;
                int e = lg * 4 + r;
                int ad = (e * 256 + feat * 2) ^ ((e & 7) << 4);
                *reinterpret_cast<unsigned short*>(wsm + ad) = f2bf(z);
            }
        }
    }

    // ---- phase E: alpha = z3 @ cW2 + cb2 ; xu atomics ----
    {
        const int e = lane >> 2, s = lane & 3;
        float sum = 0.f;
#pragma unroll
        for (int j = 0; j < 4; j++) {
            int ad = (e * 256 + s * 64 + j * 16) ^ ((e & 7) << 4);
            us8 v = *reinterpret_cast<const us8*>(wsm + ad);
#pragma unroll
            for (int k = 0; k < 8; k++)
                sum += bf2f((unsigned short)v[k]) * cW2[s * 32 + j * 8 + k];
        }
        sum += __shfl_xor(sum, 1);
        sum += __shfl_xor(sum, 2);
        if (s == 0) {
            float alpha = sum + cb2[0];
            int r = rowS[w][e];
            atomicAdd(&xu[r * 3 + 0], alpha * rpS[w][e][0]);
            atomicAdd(&xu[r * 3 + 1], alpha * rpS[w][e][1]);
            atomicAdd(&xu[r * 3 + 2], alpha * rpS[w][e][2]);
        }
    }
}

// ---------------- node update kernel (fp32 A via hi/lo MFMA) ----------------
__global__ void __launch_bounds__(256, 4) node_kernel(
    const unsigned short* __restrict__ nW1T, const unsigned short* __restrict__ nW2T,
    const float* __restrict__ nb1, const float* __restrict__ nb2,
    float* __restrict__ h_cur,
    float* __restrict__ m, float* __restrict__ x_cur, float* __restrict__ xu)
{
    __shared__ __align__(16) char smA[32 * 256 * 4];  // [32][256] fp32 [h|m]
    __shared__ unsigned short znb[32 * 128];
    const int t = threadIdx.x;
    const int n0 = blockIdx.x * 32;

#pragma unroll
    for (int i = 0; i < 8; i++) {
        int c = i * 256 + t;
        int nd = c >> 6, q = c & 63;
        const float* src = (q < 32) ? (h_cur + (size_t)(n0 + nd) * 128 + q * 4)
                                    : (m + (size_t)(n0 + nd) * 128 + (q - 32) * 4);
        f4 v = *reinterpret_cast<const f4*>(src);
        int dst = (nd * 1024 + q * 16) ^ ((nd & 7) << 5);
        *reinterpret_cast<f4*>(smA + dst) = v;
    }
    __syncthreads();

    const int lane = t & 63, w = t >> 6;
    const int wm = w & 1, wn = w >> 1;
    const int lr = lane & 15, lg = lane >> 4;
    const int nA = wm * 16 + lr;
    const int nC0 = wm * 16 + lg * 4;

    us8 afh[8], afl[8];
#pragma unroll
    for (int ks = 0; ks < 8; ks++) {
        int base = (nA * 1024 + ks * 128 + lg * 32) ^ ((nA & 7) << 5);
        f4 a0 = *reinterpret_cast<const f4*>(smA + base);
        f4 a1 = *reinterpret_cast<const f4*>(smA + base + 16);
        split8(a0, a1, afh[ks], afl[ks]);
    }
#pragma unroll
    for (int nt = 0; nt < 4; nt++) {
        int feat = wn * 64 + nt * 16 + lr;
        const unsigned short* bp = nW1T + feat * 256 + lg * 8;
        f4 a = {0.f, 0.f, 0.f, 0.f};
#pragma unroll
        for (int ks = 0; ks < 8; ks++) {
            us8 b = *reinterpret_cast<const us8*>(bp + ks * 32);
            a = mfma16(afh[ks], b, a);
            a = mfma16(afl[ks], b, a);
        }
        float bias = nb1[feat];
#pragma unroll
        for (int r = 0; r < 4; r++) {
            float z = a[r] + bias;
            z = z > 0.f ? z : 0.f;
            int nd = nC0 + r;
            int ad = (nd * 256 + feat * 2) ^ ((nd & 7) << 4);
            *reinterpret_cast<unsigned short*>(reinterpret_cast<char*>(znb) + ad) = f2bf(z);
        }
    }
    __syncthreads();

    us8 af2[4];
#pragma unroll
    for (int ks = 0; ks < 4; ks++) {
        int ad = (nA * 256 + ks * 64 + lg * 16) ^ ((nA & 7) << 4);
        af2[ks] = *reinterpret_cast<const us8*>(reinterpret_cast<char*>(znb) + ad);
    }
#pragma unroll
    for (int nt = 0; nt < 4; nt++) {
        int feat = wn * 64 + nt * 16 + lr;
        const unsigned short* bp = nW2T + feat * 128 + lg * 8;
        f4 a = {0.f, 0.f, 0.f, 0.f};
#pragma unroll
        for (int ks = 0; ks < 4; ks++)
            a = mfma16(af2[ks], *reinterpret_cast<const us8*>(bp + ks * 32), a);
        float bias = nb2[feat];
#pragma unroll
        for (int r = 0; r < 4; r++) {
            int nd = nC0 + r;
            int gi = (n0 + nd) * 128 + feat;
            h_cur[gi] = h_cur[gi] + a[r] + bias;
        }
    }

    if (t < 96) {
        int nd = t / 3, d = t - nd * 3;
        int gi = (n0 + nd) * 3 + d;
        x_cur[gi] += xu[gi];
        xu[gi] = 0.f;
    }
#pragma unroll
    for (int i = 0; i < 16; i++) m[(size_t)n0 * 128 + i * 256 + t] = 0.f;
}

__global__ void __launch_bounds__(256) writeout(
    const float* __restrict__ h_cur, const float* __restrict__ x_cur,
    float* __restrict__ out)
{
    int i = blockIdx.x * 256 + threadIdx.x;
    if (i < NN * 128) out[i] = h_cur[i];
    else {
        int j = i - NN * 128;
        if (j < NN * 3) out[i] = x_cur[j];
    }
}

extern "C" void kernel_launch(void* const* d_in, const int* in_sizes, int n_in,
                              void* d_out, int out_size, void* d_ws, size_t ws_size,
                              hipStream_t stream)
{
    (void)in_sizes; (void)n_in; (void)out_size; (void)ws_size;
    const float* h_in = (const float*)d_in[0];
    const float* x_in = (const float*)d_in[1];
    const int* eidx   = (const int*)d_in[2];
    const float* embW = (const float*)d_in[3];
    const float* embB = (const float*)d_in[4];
    const float* eW1  = (const float*)d_in[5];
    const float* eb1  = (const float*)d_in[6];
    const float* eW2  = (const float*)d_in[7];
    const float* eb2  = (const float*)d_in[8];
    const float* nW1  = (const float*)d_in[9];
    const float* nb1  = (const float*)d_in[10];
    const float* nW2  = (const float*)d_in[11];
    const float* nb2  = (const float*)d_in[12];
    const float* cW1  = (const float*)d_in[13];
    const float* cb1  = (const float*)d_in[14];
    const float* cW2  = (const float*)d_in[15];
    const float* cb2  = (const float*)d_in[16];

    char* ws = (char*)d_ws;
    size_t off = 0;
    auto alloc = [&](size_t bytes) -> char* {
        char* p = ws + off;
        off += (bytes + 255) & ~size_t(255);
        return p;
    };
    float* h_cur = (float*)alloc((size_t)NN * 128 * 4);
    float* m     = (float*)alloc((size_t)NN * 128 * 4);
    float* Pb    = (float*)alloc((size_t)NN * 128 * 4);
    unsigned short* Qb = (unsigned short*)alloc((size_t)NN * 128 * 2);
    float* x_cur = (float*)alloc((size_t)NN * 3 * 4);
    float* xu    = (float*)alloc((size_t)NN * 3 * 4);
    unsigned short* pqW  = (unsigned short*)alloc(256 * 128 * 2);
    unsigned short* eW2T = (unsigned short*)alloc(128 * 128 * 2);
    unsigned short* nW1T = (unsigned short*)alloc(128 * 256 * 2);
    unsigned short* nW2T = (unsigned short*)alloc(128 * 128 * 2);
    unsigned short* cW1T = (unsigned short*)alloc(128 * 128 * 2);
    float* ew1last = (float*)alloc(128 * 4);
    int* counters = (int*)alloc((size_t)2 * NN * 4);  // deg | cursor
    int* deg    = counters;
    int* cursor = counters + NN;
    int* offs   = (int*)alloc((size_t)(NN + 1) * 4);
    int* srow   = (int*)alloc((size_t)NE * 4);
    int* scol   = (int*)alloc((size_t)NE * 4);

    zero_kernel<<<(2 * NN + 255) / 256, 256, 0, stream>>>(counters, 2 * NN);
    prep_weights<<<449, 256, 0, stream>>>(eW1, eW2, nW1, nW2, cW1,
                                          pqW, eW2T, nW1T, nW2T, cW1T, ew1last);
    embed_init<<<NN, 128, 0, stream>>>(h_in, x_in, embW, embB,
                                       h_cur, x_cur, m, xu);
    hist_kernel<<<(NE + 255) / 256, 256, 0, stream>>>(eidx, deg);
    scan_kernel<<<1, 1024, 0, stream>>>(deg, offs);
    scatter_kernel<<<(NE + 255) / 256, 256, 0, stream>>>(eidx, offs, cursor, srow, scol);
    pq_kernel<<<NN / 32, 256, 0, stream>>>(h_cur, pqW, eb1, Pb, Qb);

    for (int l = 0; l < 2; l++) {
        edge_kernel<<<NE / 64, 256, 0, stream>>>(srow, scol, Pb, Qb, x_cur,
                                                 eW2T, cW1T, ew1last,
                                                 eb2, cb1, cb2, cW2, m, xu);
        node_kernel<<<NN / 32, 256, 0, stream>>>(nW1T, nW2T, nb1, nb2,
                                                 h_cur, m, x_cur, xu);
        if (l == 0)
            pq_kernel<<<NN / 32, 256, 0, stream>>>(h_cur, pqW, eb1, Pb, Qb);
    }
    writeout<<<(NN * 128 + NN * 3 + 255) / 256, 256, 0, stream>>>(h_cur, x_cur, (float*)d_out);
}

// Round 10
// 1203.102 us; speedup vs baseline: 1.0677x; 1.0677x over previous
//
#include <hip/hip_runtime.h>

#define NN 20000
#define NE 640000

typedef __attribute__((ext_vector_type(4))) float f4;
typedef __attribute__((ext_vector_type(8))) unsigned short us8;
typedef __attribute__((ext_vector_type(8))) __bf16 bf8;
typedef __attribute__((ext_vector_type(4))) int i4;

__device__ __forceinline__ unsigned short f2bf(float f) {
    union { float f; unsigned int u; } v; v.f = f;
    unsigned int u = v.u;
    return (unsigned short)((u + 0x7FFFu + ((u >> 16) & 1u)) >> 16);
}
__device__ __forceinline__ float bf2f(unsigned short b) {
    union { unsigned int u; float f; } v; v.u = ((unsigned int)b) << 16; return v.f;
}
__device__ __forceinline__ f4 mfma16(us8 a, us8 b, f4 c) {
    return __builtin_amdgcn_mfma_f32_16x16x32_bf16(
        __builtin_bit_cast(bf8, a), __builtin_bit_cast(bf8, b), c, 0, 0, 0);
}
__device__ __forceinline__ void split8(f4 a0, f4 a1, us8& h, us8& l) {
#pragma unroll
    for (int j = 0; j < 4; j++) {
        unsigned short hb = f2bf(a0[j]); h[j] = hb; l[j] = f2bf(a0[j] - bf2f(hb));
        unsigned short hb2 = f2bf(a1[j]); h[4 + j] = hb2; l[4 + j] = f2bf(a1[j] - bf2f(hb2));
    }
}

// ---------------- weight prep ----------------
__global__ void __launch_bounds__(256) prep_weights(
    const float* __restrict__ eW1, const float* __restrict__ eW2,
    const float* __restrict__ nW1, const float* __restrict__ nW2,
    const float* __restrict__ cW1,
    unsigned short* __restrict__ pqW, unsigned short* __restrict__ eW2T,
    unsigned short* __restrict__ nW1T, unsigned short* __restrict__ nW2T,
    unsigned short* __restrict__ cW1T, float* __restrict__ ew1last)
{
    int i = blockIdx.x * 256 + threadIdx.x;
    if (i < 32768) {
        int f = i >> 7, k = i & 127;
        float v = (f < 128) ? eW1[k * 128 + f] : eW1[(128 + k) * 128 + (f - 128)];
        pqW[i] = f2bf(v); return;
    }
    i -= 32768;
    if (i < 16384) { int f = i >> 7, k = i & 127; eW2T[i] = f2bf(eW2[k * 128 + f]); return; }
    i -= 16384;
    if (i < 32768) { int f = i >> 8, k = i & 255; nW1T[i] = f2bf(nW1[k * 128 + f]); return; }
    i -= 32768;
    if (i < 16384) { int f = i >> 7, k = i & 127; nW2T[i] = f2bf(nW2[k * 128 + f]); return; }
    i -= 16384;
    if (i < 16384) { int f = i >> 7, k = i & 127; cW1T[i] = f2bf(cW1[k * 128 + f]); return; }
    i -= 16384;
    if (i < 128) { ew1last[i] = eW1[256 * 128 + i]; }
}

// ---------------- embedding + state init ----------------
__global__ void __launch_bounds__(128) embed_init(
    const float* __restrict__ h_in, const float* __restrict__ x_in,
    const float* __restrict__ embW, const float* __restrict__ embB,
    float* __restrict__ h_cur, float* __restrict__ x_cur,
    float* __restrict__ m, float* __restrict__ xu)
{
    int n = blockIdx.x, f = threadIdx.x;
    float acc = embB[f];
#pragma unroll
    for (int p = 0; p < 16; p++) acc += h_in[n * 16 + p] * embW[p * 128 + f];
    h_cur[n * 128 + f] = acc;
    m[n * 128 + f] = 0.f;
    if (f < 3) { x_cur[n * 3 + f] = x_in[n * 3 + f]; xu[n * 3 + f] = 0.f; }
}

// ---------------- CSR sort ----------------
__global__ void __launch_bounds__(256) zero_kernel(int* __restrict__ p, int n) {
    int i = blockIdx.x * 256 + threadIdx.x;
    if (i < n) p[i] = 0;
}

__global__ void __launch_bounds__(256) hist_kernel(const int* __restrict__ eidx,
                                                   int* __restrict__ deg) {
    int e = blockIdx.x * 256 + threadIdx.x;
    if (e < NE) atomicAdd(&deg[eidx[e]], 1);
}

__global__ void __launch_bounds__(1024) scan_kernel(const int* __restrict__ deg,
                                                    int* __restrict__ offs) {
    __shared__ int ssum[1024];
    const int t = threadIdx.x;
    const int base = t * 20;
    int loc[20];
    int s = 0;
#pragma unroll
    for (int i = 0; i < 20; i++) {
        int v = (base + i < NN) ? deg[base + i] : 0;
        loc[i] = s; s += v;
    }
    ssum[t] = s;
    __syncthreads();
    for (int d = 1; d < 1024; d <<= 1) {
        int v = (t >= d) ? ssum[t - d] : 0;
        __syncthreads();
        ssum[t] += v;
        __syncthreads();
    }
    int excl = (t == 0) ? 0 : ssum[t - 1];
#pragma unroll
    for (int i = 0; i < 20; i++)
        if (base + i < NN) offs[base + i] = excl + loc[i];
    if (t == 1023) offs[NN] = ssum[1023];
}

__global__ void __launch_bounds__(256) scatter_kernel(
    const int* __restrict__ eidx, const int* __restrict__ offs,
    int* __restrict__ cursor, int* __restrict__ srow, int* __restrict__ scol)
{
    int e = blockIdx.x * 256 + threadIdx.x;
    if (e >= NE) return;
    int r = eidx[e];
    int pos = offs[r] + atomicAdd(&cursor[r], 1);
    srow[pos] = r;
    scol[pos] = eidx[NE + e];
}

// ---------------- pq_kernel: P(+eb1) fp32 | Q bf16 = h @ pqW^T --------------
__global__ void __launch_bounds__(256, 2) pq_kernel(
    const float* __restrict__ h_cur, const unsigned short* __restrict__ pqW,
    const float* __restrict__ eb1,
    float* __restrict__ Pb, unsigned short* __restrict__ Qb)
{
    __shared__ __align__(16) char smA[32 * 128 * 4];  // 16KB fp32 h tile
    const int t = threadIdx.x;
    const int n0 = blockIdx.x * 32;

#pragma unroll
    for (int i = 0; i < 4; i++) {
        int c = i * 256 + t;              // 0..1023 f4-chunks
        int nd = c >> 5, q = c & 31;
        f4 v = *reinterpret_cast<const f4*>(h_cur + (size_t)(n0 + nd) * 128 + q * 4);
        int dst = (nd * 512 + q * 16) ^ ((nd & 7) << 5);
        *reinterpret_cast<f4*>(smA + dst) = v;
    }
    __syncthreads();

    const int lane = t & 63, w = t >> 6;
    const int lr = lane & 15, lg = lane >> 4;

    us8 ah[2][4], al[2][4];
#pragma unroll
    for (int rb = 0; rb < 2; rb++) {
        int row = rb * 16 + lr;
#pragma unroll
        for (int ks = 0; ks < 4; ks++) {
            int base = (row * 512 + ks * 128 + lg * 32) ^ ((row & 7) << 5);
            f4 a0 = *reinterpret_cast<const f4*>(smA + base);
            f4 a1 = *reinterpret_cast<const f4*>(smA + base + 16);
            split8(a0, a1, ah[rb][ks], al[rb][ks]);
        }
    }
#pragma unroll
    for (int rb = 0; rb < 2; rb++) {
#pragma unroll
        for (int nt = 0; nt < 4; nt++) {
            int feat = w * 64 + nt * 16 + lr;
            const unsigned short* bp = pqW + feat * 128 + lg * 8;
            f4 a = {0.f, 0.f, 0.f, 0.f};
#pragma unroll
            for (int ks = 0; ks < 4; ks++) {
                us8 b = *reinterpret_cast<const us8*>(bp + ks * 32);
                a = mfma16(ah[rb][ks], b, a);
                a = mfma16(al[rb][ks], b, a);
            }
#pragma unroll
            for (int r = 0; r < 4; r++) {
                int n = n0 + rb * 16 + lg * 4 + r;
                if (feat < 128) Pb[(size_t)n * 128 + feat] = a[r] + eb1[feat];
                else            Qb[(size_t)n * 128 + feat - 128] = f2bf(a[r]);
            }
        }
    }
}

// ---------------- edge kernel: 64 edges/block, 4 independent waves ----------
// Per wave: 16 edges, no barriers, 4KB LDS slice (e_ij bf16 [16][128] only).
// Phase A: z1 computed DIRECTLY in MFMA A-frag layout (registers).
// Phase D: GEMM3 + alpha fused in registers (shfl reduce), no z3 LDS.
__global__ void __launch_bounds__(256, 6) edge_kernel(
    const int* __restrict__ srow, const int* __restrict__ scol,
    const float* __restrict__ Pb, const unsigned short* __restrict__ Qb,
    const float* __restrict__ x_cur,
    const unsigned short* __restrict__ eW2T, const unsigned short* __restrict__ cW1T,
    const float* __restrict__ ew1last,
    const float* __restrict__ eb2, const float* __restrict__ cb1,
    const float* __restrict__ cb2, const float* __restrict__ cW2,
    float* __restrict__ m, float* __restrict__ xu)
{
    __shared__ __align__(16) unsigned short ebuf[4][2048];  // 4KB/wave e_ij bf16
    __shared__ int rowS[4][16];
    __shared__ int colS[4][16];
    __shared__ float rpS[4][16][3];
    __shared__ float rdS[4][16];

    const int t = threadIdx.x;
    const int w = t >> 6, lane = t & 63;
    char* wsm = reinterpret_cast<char*>(ebuf[w]);
    const int e0 = blockIdx.x * 64 + w * 16;

    // meta (lanes 0-15; within-wave DS ordering, no barrier needed)
    if (lane < 16) {
        int r = srow[e0 + lane], c = scol[e0 + lane];
        rowS[w][lane] = r; colS[w][lane] = c;
        float dx = x_cur[r * 3 + 0] - x_cur[c * 3 + 0];
        float dy = x_cur[r * 3 + 1] - x_cur[c * 3 + 1];
        float dz = x_cur[r * 3 + 2] - x_cur[c * 3 + 2];
        rpS[w][lane][0] = dx; rpS[w][lane][1] = dy; rpS[w][lane][2] = dz;
        rdS[w][lane] = dx * dx + dy * dy + dz * dz;
    }

    const int lr = lane & 15, lg = lane >> 4;

    // ---- phase A: z1 A-frags in registers (edge lr, k-chunk ks*32+lg*8) ----
    us8 af[4];
    {
        const int rowE = rowS[w][lr];
        const int colE = colS[w][lr];
        const float rd = rdS[w][lr];
        const float* pp = Pb + (size_t)rowE * 128;
        const unsigned short* qp = Qb + (size_t)colE * 128;
#pragma unroll
        for (int ks = 0; ks < 4; ks++) {
            int f = ks * 32 + lg * 8;
            f4 p0 = *reinterpret_cast<const f4*>(pp + f);
            f4 p1 = *reinterpret_cast<const f4*>(pp + f + 4);
            us8 q  = *reinterpret_cast<const us8*>(qp + f);
            f4 w0 = *reinterpret_cast<const f4*>(ew1last + f);
            f4 w1 = *reinterpret_cast<const f4*>(ew1last + f + 4);
            us8 z;
#pragma unroll
            for (int k = 0; k < 4; k++) {
                float a = p0[k] + bf2f((unsigned short)q[k])     + rd * w0[k];
                float b = p1[k] + bf2f((unsigned short)q[4 + k]) + rd * w1[k];
                a = a > 0.f ? a : 0.f;
                b = b > 0.f ? b : 0.f;
                z[k] = f2bf(a); z[4 + k] = f2bf(b);
            }
            af[ks] = z;
        }
    }

    // ---- phase B: GEMM2 e_ij = z1 @ eW2 + eb2 -> bf16 wave LDS ----
#pragma unroll
    for (int nt = 0; nt < 8; nt++) {
        int feat = nt * 16 + lr;
        const unsigned short* bp = eW2T + feat * 128 + lg * 8;
        f4 a = {0.f, 0.f, 0.f, 0.f};
#pragma unroll
        for (int ks = 0; ks < 4; ks++)
            a = mfma16(af[ks], *reinterpret_cast<const us8*>(bp + ks * 32), a);
        float bias = eb2[feat];
#pragma unroll
        for (int r = 0; r < 4; r++) {
            int e = lg * 4 + r;
            int ad = (e * 256 + feat * 2) ^ ((e & 7) << 4);
            *reinterpret_cast<unsigned short*>(wsm + ad) = f2bf(a[r] + bias);
        }
    }

    // ---- phase C: m-accum (2 feats/lane, fp32, run-aggregated atomics) ----
    {
        const int f0 = lane;
        float a0 = 0.f, a1 = 0.f;
        int prow = rowS[w][0];
#pragma unroll
        for (int e = 0; e < 16; e++) {
            int r = rowS[w][e];
            if (r != prow) {
                atomicAdd(&m[(size_t)prow * 128 + f0], a0);
                atomicAdd(&m[(size_t)prow * 128 + f0 + 64], a1);
                a0 = a1 = 0.f; prow = r;
            }
            a0 += bf2f(*reinterpret_cast<const unsigned short*>(
                    wsm + ((e * 256 + f0 * 2) ^ ((e & 7) << 4))));
            a1 += bf2f(*reinterpret_cast<const unsigned short*>(
                    wsm + ((e * 256 + (f0 + 64) * 2) ^ ((e & 7) << 4))));
        }
        atomicAdd(&m[(size_t)prow * 128 + f0], a0);
        atomicAdd(&m[(size_t)prow * 128 + f0 + 64], a1);
    }

    // ---- phase D: GEMM3 + alpha fused (registers, shfl reduce) ----
    {
        us8 a3[4];
#pragma unroll
        for (int ks = 0; ks < 4; ks++) {
            int ad = (lr * 256 + (ks * 32 + lg * 8) * 2) ^ ((lr & 7) << 4);
            a3[ks] = *reinterpret_cast<const us8*>(wsm + ad);
        }
        float partial[4] = {0.f, 0.f, 0.f, 0.f};
#pragma unroll
        for (int nt = 0; nt < 8; nt++) {
            int feat = nt * 16 + lr;
            const unsigned short* bp = cW1T + feat * 128 + lg * 8;
            f4 a = {0.f, 0.f, 0.f, 0.f};
#pragma unroll
            for (int ks = 0; ks < 4; ks++)
                a = mfma16(a3[ks], *reinterpret_cast<const us8*>(bp + ks * 32), a);
            float bias = cb1[feat], wv = cW2[feat];
#pragma unroll
            for (int r = 0; r < 4; r++) {
                float z = a[r] + bias;
                z = z > 0.f ? z : 0.f;
                partial[r] += z * wv;
            }
        }
#pragma unroll
        for (int r = 0; r < 4; r++) {
            partial[r] += __shfl_xor(partial[r], 1);
            partial[r] += __shfl_xor(partial[r], 2);
            partial[r] += __shfl_xor(partial[r], 4);
            partial[r] += __shfl_xor(partial[r], 8);
        }
        if (lr < 4) {
            int e = lg * 4 + lr;
            float alpha = ((lr == 0) ? partial[0] : (lr == 1) ? partial[1]
                          : (lr == 2) ? partial[2] : partial[3]) + cb2[0];
            int r = rowS[w][e];
            atomicAdd(&xu[r * 3 + 0], alpha * rpS[w][e][0]);
            atomicAdd(&xu[r * 3 + 1], alpha * rpS[w][e][1]);
            atomicAdd(&xu[r * 3 + 2], alpha * rpS[w][e][2]);
        }
    }
}

// ---------------- node update kernel (fp32 A via hi/lo MFMA) ----------------
__global__ void __launch_bounds__(256, 4) node_kernel(
    const unsigned short* __restrict__ nW1T, const unsigned short* __restrict__ nW2T,
    const float* __restrict__ nb1, const float* __restrict__ nb2,
    float* __restrict__ h_cur,
    float* __restrict__ m, float* __restrict__ x_cur, float* __restrict__ xu)
{
    __shared__ __align__(16) char smA[32 * 256 * 4];  // [32][256] fp32 [h|m]
    __shared__ unsigned short znb[32 * 128];
    const int t = threadIdx.x;
    const int n0 = blockIdx.x * 32;

#pragma unroll
    for (int i = 0; i < 8; i++) {
        int c = i * 256 + t;
        int nd = c >> 6, q = c & 63;
        const float* src = (q < 32) ? (h_cur + (size_t)(n0 + nd) * 128 + q * 4)
                                    : (m + (size_t)(n0 + nd) * 128 + (q - 32) * 4);
        f4 v = *reinterpret_cast<const f4*>(src);
        int dst = (nd * 1024 + q * 16) ^ ((nd & 7) << 5);
        *reinterpret_cast<f4*>(smA + dst) = v;
    }
    __syncthreads();

    const int lane = t & 63, w = t >> 6;
    const int wm = w & 1, wn = w >> 1;
    const int lr = lane & 15, lg = lane >> 4;
    const int nA = wm * 16 + lr;
    const int nC0 = wm * 16 + lg * 4;

    us8 afh[8], afl[8];
#pragma unroll
    for (int ks = 0; ks < 8; ks++) {
        int base = (nA * 1024 + ks * 128 + lg * 32) ^ ((nA & 7) << 5);
        f4 a0 = *reinterpret_cast<const f4*>(smA + base);
        f4 a1 = *reinterpret_cast<const f4*>(smA + base + 16);
        split8(a0, a1, afh[ks], afl[ks]);
    }
#pragma unroll
    for (int nt = 0; nt < 4; nt++) {
        int feat = wn * 64 + nt * 16 + lr;
        const unsigned short* bp = nW1T + feat * 256 + lg * 8;
        f4 a = {0.f, 0.f, 0.f, 0.f};
#pragma unroll
        for (int ks = 0; ks < 8; ks++) {
            us8 b = *reinterpret_cast<const us8*>(bp + ks * 32);
            a = mfma16(afh[ks], b, a);
            a = mfma16(afl[ks], b, a);
        }
        float bias = nb1[feat];
#pragma unroll
        for (int r = 0; r < 4; r++) {
            float z = a[r] + bias;
            z = z > 0.f ? z : 0.f;
            int nd = nC0 + r;
            int ad = (nd * 256 + feat * 2) ^ ((nd & 7) << 4);
            *reinterpret_cast<unsigned short*>(reinterpret_cast<char*>(znb) + ad) = f2bf(z);
        }
    }
    __syncthreads();

    us8 af2[4];
#pragma unroll
    for (int ks = 0; ks < 4; ks++) {
        int ad = (nA * 256 + ks * 64 + lg * 16) ^ ((nA & 7) << 4);
        af2[ks] = *reinterpret_cast<const us8*>(reinterpret_cast<char*>(znb) + ad);
    }
#pragma unroll
    for (int nt = 0; nt < 4; nt++) {
        int feat = wn * 64 + nt * 16 + lr;
        const unsigned short* bp = nW2T + feat * 128 + lg * 8;
        f4 a = {0.f, 0.f, 0.f, 0.f};
#pragma unroll
        for (int ks = 0; ks < 4; ks++)
            a = mfma16(af2[ks], *reinterpret_cast<const us8*>(bp + ks * 32), a);
        float bias = nb2[feat];
#pragma unroll
        for (int r = 0; r < 4; r++) {
            int nd = nC0 + r;
            int gi = (n0 + nd) * 128 + feat;
            h_cur[gi] = h_cur[gi] + a[r] + bias;
        }
    }

    if (t < 96) {
        int nd = t / 3, d = t - nd * 3;
        int gi = (n0 + nd) * 3 + d;
        x_cur[gi] += xu[gi];
        xu[gi] = 0.f;
    }
#pragma unroll
    for (int i = 0; i < 16; i++) m[(size_t)n0 * 128 + i * 256 + t] = 0.f;
}

__global__ void __launch_bounds__(256) writeout(
    const float* __restrict__ h_cur, const float* __restrict__ x_cur,
    float* __restrict__ out)
{
    int i = blockIdx.x * 256 + threadIdx.x;
    if (i < NN * 128) out[i] = h_cur[i];
    else {
        int j = i - NN * 128;
        if (j < NN * 3) out[i] = x_cur[j];
    }
}

extern "C" void kernel_launch(void* const* d_in, const int* in_sizes, int n_in,
                              void* d_out, int out_size, void* d_ws, size_t ws_size,
                              hipStream_t stream)
{
    (void)in_sizes; (void)n_in; (void)out_size; (void)ws_size;
    const float* h_in = (const float*)d_in[0];
    const float* x_in = (const float*)d_in[1];
    const int* eidx   = (const int*)d_in[2];
    const float* embW = (const float*)d_in[3];
    const float* embB = (const float*)d_in[4];
    const float* eW1  = (const float*)d_in[5];
    const float* eb1  = (const float*)d_in[6];
    const float* eW2  = (const float*)d_in[7];
    const float* eb2  = (const float*)d_in[8];
    const float* nW1  = (const float*)d_in[9];
    const float* nb1  = (const float*)d_in[10];
    const float* nW2  = (const float*)d_in[11];
    const float* nb2  = (const float*)d_in[12];
    const float* cW1  = (const float*)d_in[13];
    const float* cb1  = (const float*)d_in[14];
    const float* cW2  = (const float*)d_in[15];
    const float* cb2  = (const float*)d_in[16];

    char* ws = (char*)d_ws;
    size_t off = 0;
    auto alloc = [&](size_t bytes) -> char* {
        char* p = ws + off;
        off += (bytes + 255) & ~size_t(255);
        return p;
    };
    float* h_cur = (float*)alloc((size_t)NN * 128 * 4);
    float* m     = (float*)alloc((size_t)NN * 128 * 4);
    float* Pb    = (float*)alloc((size_t)NN * 128 * 4);
    unsigned short* Qb = (unsigned short*)alloc((size_t)NN * 128 * 2);
    float* x_cur = (float*)alloc((size_t)NN * 3 * 4);
    float* xu    = (float*)alloc((size_t)NN * 3 * 4);
    unsigned short* pqW  = (unsigned short*)alloc(256 * 128 * 2);
    unsigned short* eW2T = (unsigned short*)alloc(128 * 128 * 2);
    unsigned short* nW1T = (unsigned short*)alloc(128 * 256 * 2);
    unsigned short* nW2T = (unsigned short*)alloc(128 * 128 * 2);
    unsigned short* cW1T = (unsigned short*)alloc(128 * 128 * 2);
    float* ew1last = (float*)alloc(128 * 4);
    int* counters = (int*)alloc((size_t)2 * NN * 4);  // deg | cursor
    int* deg    = counters;
    int* cursor = counters + NN;
    int* offs   = (int*)alloc((size_t)(NN + 1) * 4);
    int* srow   = (int*)alloc((size_t)NE * 4);
    int* scol   = (int*)alloc((size_t)NE * 4);

    zero_kernel<<<(2 * NN + 255) / 256, 256, 0, stream>>>(counters, 2 * NN);
    prep_weights<<<449, 256, 0, stream>>>(eW1, eW2, nW1, nW2, cW1,
                                          pqW, eW2T, nW1T, nW2T, cW1T, ew1last);
    embed_init<<<NN, 128, 0, stream>>>(h_in, x_in, embW, embB,
                                       h_cur, x_cur, m, xu);
    hist_kernel<<<(NE + 255) / 256, 256, 0, stream>>>(eidx, deg);
    scan_kernel<<<1, 1024, 0, stream>>>(deg, offs);
    scatter_kernel<<<(NE + 255) / 256, 256, 0, stream>>>(eidx, offs, cursor, srow, scol);
    pq_kernel<<<NN / 32, 256, 0, stream>>>(h_cur, pqW, eb1, Pb, Qb);

    for (int l = 0; l < 2; l++) {
        edge_kernel<<<NE / 64, 256, 0, stream>>>(srow, scol, Pb, Qb, x_cur,
                                                 eW2T, cW1T, ew1last,
                                                 eb2, cb1, cb2, cW2, m, xu);
        node_kernel<<<NN / 32, 256, 0, stream>>>(nW1T, nW2T, nb1, nb2,
                                                 h_cur, m, x_cur, xu);
        if (l == 0)
            pq_kernel<<<NN / 32, 256, 0, stream>>>(h_cur, pqW, eb1, Pb, Qb);
    }
    writeout<<<(NN * 128 + NN * 3 + 255) / 256, 256, 0, stream>>>(h_cur, x_cur, (float*)d_out);
}